// Round 14
// baseline (1599.652 us; speedup 1.0000x reference)
//
#include <hip/hip_runtime.h>
#include <math.h>

// ---- problem constants ----
constexpr int BATCH  = 2;
constexpr int SEQ    = 1024;
constexpr int DIM    = 768;
constexpr int NLAYER = 4;
constexpr int NHEAD  = 12;
constexpr int HDIM   = 64;
constexpr int NEXP   = 4;
constexpr int FFDIM  = 3072;
constexpr int VOCAB  = 50257;
constexpr int NDIM   = NEXP * DIM;   // 3072
constexpr int NC     = NEXP*NEXP + 2*NEXP; // 24
constexpr int NTOK   = BATCH * SEQ;  // 2048

using bf16x8 = __attribute__((ext_vector_type(8))) __bf16;
using f32x4  = __attribute__((ext_vector_type(4))) float;
using u16x8  = __attribute__((ext_vector_type(8))) unsigned short;
using u16x4  = __attribute__((ext_vector_type(4))) unsigned short;
using u32x4  = __attribute__((ext_vector_type(4))) unsigned int;

__device__ inline unsigned short f2bf(float f){
  unsigned u = __builtin_bit_cast(unsigned, f);
  u += 0x7fffu + ((u >> 16) & 1u);      // round-to-nearest-even
  return (unsigned short)(u >> 16);
}
__device__ inline float bf2f(unsigned short v){
  return __builtin_bit_cast(float, ((unsigned)v) << 16);
}
__device__ inline bf16x8 as_bf(u16x8 v){ return __builtin_bit_cast(bf16x8, v); }

// ---- workspace layout (float units) — R8 layout ----
constexpr size_t SZ_X   = (size_t)NTOK * NEXP * DIM;   // 6291456
constexpr size_t SZ_T   = (size_t)NTOK * DIM;          // 1572864
constexpr size_t O_X    = 0;
constexpr size_t O_X2   = O_X  + SZ_X;
constexpr size_t O_TMP  = O_X2 + SZ_X;                 // y bf16 (u16 SZ_T)
constexpr size_t O_BIG  = O_TMP + SZ_T;                // qkv/fc1-out bf16
constexpr size_t O_LNB  = O_BIG + (size_t)NTOK*2304;
constexpr size_t O_T1B  = O_LNB + SZ_T/2;
constexpr size_t O_COEF = O_T1B + SZ_T/2;
constexpr size_t O_WT   = O_COEF + (size_t)NTOK*NC;    // per-layer bf16 weights
// tokbf overlays floats [0 .. 19298688) (dead at lm_head time)
constexpr size_t O_LNF  = 19298688;                    // final-LN bf16 (786432 f)

// ---- wave-level reduce (64 lanes) ----
__device__ inline float wred_sum(float v){
#pragma unroll
  for (int m=32;m>=1;m>>=1) v += __shfl_xor(v,m);
  return v;
}

// ============================ fused mhc: [combine] + coef(sinkhorn) + pre-mix + LN ============================
template<bool FIRST>
__global__ __launch_bounds__(256) void k_mhc(const int* __restrict__ ids,
                                             const float* __restrict__ tokf,
                                             const float* __restrict__ posf,
                                             const float* __restrict__ xin,
                                             const unsigned short* __restrict__ y,
                                             float* __restrict__ xout,
                                             const float* __restrict__ W,
                                             const float* __restrict__ bb,
                                             const float* __restrict__ alpha_p,
                                             const float* __restrict__ g,
                                             const float* __restrict__ lnb_,
                                             float* __restrict__ coef,
                                             unsigned short* __restrict__ lnout){
  const int t = blockIdx.x, tid = threadIdx.x;
  const int w = tid >> 6;
  __shared__ float wred[4], w2[4];
  __shared__ float accw[4][NC];
  __shared__ float cfl[NC];

  float xp[3][4];
  float ss = 0.f;

  if constexpr (FIRST){
    const float* te = tokf + (size_t)ids[t]*DIM;
    const float* pe = posf + (size_t)(t % SEQ)*DIM;
#pragma unroll
    for (int k=0;k<3;k++){
      int d = tid + k*256;
      float v = te[d] + pe[d];
#pragma unroll
      for (int n=0;n<4;n++){
        xp[k][n] = v;
        xout[(size_t)t*NDIM + n*DIM + d] = v;
      }
      ss += 4.f*v*v;
    }
  } else {
    float cfp[20];
    const float* cp = coef + (size_t)t*NC;
#pragma unroll
    for (int j=0;j<16;j++) cfp[j] = cp[j];
#pragma unroll
    for (int j=0;j<4;j++) cfp[16+j] = cp[20+j];
    const float* xt = xin + (size_t)t*NDIM;
#pragma unroll
    for (int k=0;k<3;k++){
      int d = tid + k*256;
      float xm[4];
#pragma unroll
      for (int m=0;m<4;m++) xm[m] = xt[m*DIM + d];
      float yv = bf2f(y[(size_t)t*DIM + d]);
#pragma unroll
      for (int n=0;n<4;n++){
        float o = cfp[16+n]*yv;
#pragma unroll
        for (int m=0;m<4;m++) o += cfp[n*4+m]*xm[m];
        xp[k][n] = o;
        xout[(size_t)t*NDIM + n*DIM + d] = o;
        ss += o*o;
      }
    }
  }

  ss = wred_sum(ss);
  float acc[NC];
#pragma unroll
  for (int j=0;j<NC;j++) acc[j]=0.f;
#pragma unroll
  for (int k=0;k<3;k++){
    int d = tid + k*256;
#pragma unroll
    for (int n=0;n<4;n++){
      float v = xp[k][n];
      const float* wr = W + (size_t)(n*DIM + d)*NC;
#pragma unroll
      for (int j=0;j<NC;j++) acc[j] += v*wr[j];
    }
  }
#pragma unroll
  for (int j=0;j<NC;j++){
#pragma unroll
    for (int m=32;m>=1;m>>=1) acc[j] += __shfl_xor(acc[j], m);
  }
  if ((tid&63)==0){
    wred[w] = ss;
#pragma unroll
    for (int j=0;j<NC;j++) accw[w][j] = acc[j];
  }
  __syncthreads();
  float rfac = rsqrtf((wred[0]+wred[1]+wred[2]+wred[3])/(float)NDIM + 1e-6f);

  const float alpha = alpha_p[0];
  float* cfg = coef + (size_t)t*NC;
  if (tid < 16){
    float lmv = (accw[0][tid]+accw[1][tid]+accw[2][tid]+accw[3][tid])*rfac*alpha + bb[tid];
#pragma unroll
    for (int it=0; it<10; ++it){
      float mx = fmaxf(lmv, __shfl_xor(lmv,1)); mx = fmaxf(mx, __shfl_xor(mx,2));
      float se = expf(lmv-mx); se += __shfl_xor(se,1); se += __shfl_xor(se,2);
      lmv -= mx + logf(se);
      mx = fmaxf(lmv, __shfl_xor(lmv,4)); mx = fmaxf(mx, __shfl_xor(mx,8));
      se = expf(lmv-mx); se += __shfl_xor(se,4); se += __shfl_xor(se,8);
      lmv -= mx + logf(se);
    }
    float hm = expf(lmv);
    cfl[tid] = hm;
    cfg[tid] = hm;
  } else if (tid < 24){
    cfl[tid] = (accw[0][tid]+accw[1][tid]+accw[2][tid]+accw[3][tid])*rfac*alpha + bb[tid];
  }
  __syncthreads();
  if (tid == 0){
    float l0=cfl[16], l1=cfl[17], l2=cfl[18], l3=cfl[19];
    float pm = fmaxf(fmaxf(l0,l1),fmaxf(l2,l3));
    float e0=expf(l0-pm), e1=expf(l1-pm), e2=expf(l2-pm), e3=expf(l3-pm);
    float es=e0+e1+e2+e3;
    cfl[16]=e0/es; cfl[17]=e1/es; cfl[18]=e2/es; cfl[19]=e3/es;
#pragma unroll
    for (int j=20;j<24;j++) cfl[j] = 1.f/(1.f+expf(-cfl[j]));
#pragma unroll
    for (int j=16;j<24;j++) cfg[j] = cfl[j];
  }
  __syncthreads();

  float p0=cfl[16], p1=cfl[17], p2=cfl[18], p3=cfl[19];
  float h[3], s1=0.f, s2=0.f;
#pragma unroll
  for (int k=0;k<3;k++){
    float v = p0*xp[k][0] + p1*xp[k][1] + p2*xp[k][2] + p3*xp[k][3];
    h[k]=v; s1+=v; s2+=v*v;
  }
  s1 = wred_sum(s1); s2 = wred_sum(s2);
  if ((tid&63)==0){ wred[w]=s1; w2[w]=s2; }
  __syncthreads();
  float mu  = (wred[0]+wred[1]+wred[2]+wred[3])/(float)DIM;
  float var = (w2[0]+w2[1]+w2[2]+w2[3])/(float)DIM - mu*mu;
  float inv = rsqrtf(var + 1e-5f);
#pragma unroll
  for (int k=0;k<3;k++){
    int d = tid + k*256;
    lnout[(size_t)t*DIM+d] = f2bf((h[k]-mu)*inv*g[d] + lnb_[d]);
  }
}

// ============================ tail: combine-sum + final LN -> bf16 ============================
__global__ __launch_bounds__(256) void k_csumln(const float* __restrict__ xin,
                                                const float* __restrict__ coef,
                                                const unsigned short* __restrict__ y,
                                                const float* __restrict__ g,
                                                const float* __restrict__ bb,
                                                unsigned short* __restrict__ out){
  const int t = blockIdx.x, tid = threadIdx.x;
  const int w = tid >> 6;
  const float* cp = coef + (size_t)t*NC;
  float cs[4];
#pragma unroll
  for (int m=0;m<4;m++) cs[m] = cp[m] + cp[4+m] + cp[8+m] + cp[12+m];
  float ps = cp[20]+cp[21]+cp[22]+cp[23];
  const float* xt = xin + (size_t)t*NDIM;
  float h[3], s1=0.f, s2=0.f;
#pragma unroll
  for (int k=0;k<3;k++){
    int d = tid + k*256;
    float v = ps * bf2f(y[(size_t)t*DIM + d]);
#pragma unroll
    for (int m=0;m<4;m++) v += cs[m]*xt[m*DIM + d];
    h[k]=v; s1+=v; s2+=v*v;
  }
  __shared__ float r1[4], r2[4];
  s1 = wred_sum(s1); s2 = wred_sum(s2);
  if ((tid&63)==0){ r1[w]=s1; r2[w]=s2; }
  __syncthreads();
  float mu  = (r1[0]+r1[1]+r1[2]+r1[3])/(float)DIM;
  float var = (r2[0]+r2[1]+r2[2]+r2[3])/(float)DIM - mu*mu;
  float inv = rsqrtf(var + 1e-5f);
#pragma unroll
  for (int k=0;k<3;k++){
    int d = tid + k*256;
    out[(size_t)t*DIM+d] = f2bf((h[k]-mu)*inv*g[d] + bb[d]);
  }
}

// ============================ flash attention (MFMA, swapped QK^T -> S^T) — R8-proven ============================
__global__ __launch_bounds__(256) void k_fattn(const unsigned short* __restrict__ qkv,
                                               unsigned short* __restrict__ out){
  const int qb = gridDim.x - 1 - blockIdx.x;   // longest blocks dispatched first
  const int h = blockIdx.y, b = blockIdx.z;
  const int tid = threadIdx.x;
  const int l = tid & 63, w = tid >> 6;
  const int lr = l & 15, lh = l >> 4;
  const int qw = qb*64 + w*16;
  constexpr int LDV = 68;
  __shared__ unsigned short Vt[64*LDV];        // V^T [d][k]

  const unsigned short* base = qkv + (size_t)b*SEQ*2304;

  u16x8 qa[2];
  {
    const unsigned short* qp = base + (size_t)(qw + lr)*2304 + h*64 + lh*8;
    qa[0] = *(const u16x8*)qp;
    qa[1] = *(const u16x8*)(qp + 32);
  }

  f32x4 o[4];
#pragma unroll
  for (int df=0; df<4; df++) o[df] = (f32x4){0.f,0.f,0.f,0.f};
  float m_run = -1e30f, l_run = 0.f;
  const int qg = qw + lr;

  const int kTiles = qb + 1;
  for (int t=0; t<kTiles; ++t){
    const int k0 = t*64;
    __syncthreads();
#pragma unroll
    for (int p=0;p<2;p++){
      int idx = p*256 + tid;
      int k  = (idx >> 4) * 2;
      int d0 = (idx & 15) * 4;
      const unsigned short* vp = base + (size_t)(k0+k)*2304 + 1536 + h*64 + d0;
      u16x4 v0 = *(const u16x4*)vp;
      u16x4 v1 = *(const u16x4*)(vp + 2304);
#pragma unroll
      for (int j=0;j<4;j++){
        unsigned pkv = (unsigned)v0[j] | ((unsigned)v1[j] << 16);
        *(unsigned*)&Vt[(d0+j)*LDV + k] = pkv;
      }
    }
    __syncthreads();

    f32x4 s[4];
#pragma unroll
    for (int kf=0;kf<4;kf++) s[kf] = (f32x4){0.f,0.f,0.f,0.f};
#pragma unroll
    for (int ks=0;ks<2;ks++){
#pragma unroll
      for (int kf=0;kf<4;kf++){
        u16x8 kb = *(const u16x8*)(base + (size_t)(k0 + kf*16 + lr)*2304 + 768 + h*64 + ks*32 + lh*8);
        s[kf] = __builtin_amdgcn_mfma_f32_16x16x32_bf16(as_bf(kb), as_bf(qa[ks]), s[kf], 0,0,0);
      }
    }

    float sc[4][4];
#pragma unroll
    for (int kf=0;kf<4;kf++){
      int kg0 = k0 + kf*16 + lh*4;
#pragma unroll
      for (int r=0;r<4;r++)
        sc[kf][r] = (kg0 + r <= qg) ? s[kf][r]*0.125f : -1e30f;
    }
    float mt = sc[0][0];
#pragma unroll
    for (int kf=0;kf<4;kf++)
#pragma unroll
      for (int r=0;r<4;r++) mt = fmaxf(mt, sc[kf][r]);
    mt = fmaxf(mt, __shfl_xor(mt, 16));
    mt = fmaxf(mt, __shfl_xor(mt, 32));
    float mn = fmaxf(m_run, mt);
    float c  = __expf(m_run - mn);
    m_run = mn;
    float p[4][4];
    float rs = 0.f;
#pragma unroll
    for (int kf=0;kf<4;kf++)
#pragma unroll
      for (int r=0;r<4;r++){
        float pv = __expf(sc[kf][r] - mn);
        p[kf][r] = pv;
        rs += pv;
      }
    rs += __shfl_xor(rs, 16);
    rs += __shfl_xor(rs, 32);
    l_run = l_run*c + rs;

    float cq[4];
#pragma unroll
    for (int r=0;r<4;r++) cq[r] = __shfl(c, lh*4 + r);
#pragma unroll
    for (int df=0;df<4;df++)
#pragma unroll
      for (int r=0;r<4;r++) o[df][r] *= cq[r];

    unsigned pk[4][2];
#pragma unroll
    for (int kf=0;kf<4;kf++){
      pk[kf][0] = (unsigned)f2bf(p[kf][0]) | ((unsigned)f2bf(p[kf][1]) << 16);
      pk[kf][1] = (unsigned)f2bf(p[kf][2]) | ((unsigned)f2bf(p[kf][3]) << 16);
    }
    const int srcA = lr + (lh&1)*32;
    const int srcB = srcA + 16;
    const bool hi = (lh>>1)&1;
#pragma unroll
    for (int ks=0;ks<2;ks++){
      unsigned s00 = __shfl(pk[ks*2  ][0], srcA), s01 = __shfl(pk[ks*2  ][1], srcA);
      unsigned s10 = __shfl(pk[ks*2+1][0], srcA), s11 = __shfl(pk[ks*2+1][1], srcA);
      unsigned t00 = __shfl(pk[ks*2  ][0], srcB), t01 = __shfl(pk[ks*2  ][1], srcB);
      unsigned t10 = __shfl(pk[ks*2+1][0], srcB), t11 = __shfl(pk[ks*2+1][1], srcB);
      u32x4 paw;
      paw[0] = hi ? s10 : s00;
      paw[1] = hi ? s11 : s01;
      paw[2] = hi ? t10 : t00;
      paw[3] = hi ? t11 : t01;
      bf16x8 pa = __builtin_bit_cast(bf16x8, paw);
#pragma unroll
      for (int df=0;df<4;df++){
        u16x8 vb = *(const u16x8*)&Vt[(df*16 + lr)*LDV + ks*32 + lh*8];
        o[df] = __builtin_amdgcn_mfma_f32_16x16x32_bf16(pa, as_bf(vb), o[df], 0,0,0);
      }
    }
  }

  float linv[4];
#pragma unroll
  for (int r=0;r<4;r++) linv[r] = 1.f/__shfl(l_run, lh*4 + r);
#pragma unroll
  for (int df=0;df<4;df++)
#pragma unroll
    for (int r=0;r<4;r++){
      int qrow = qw + lh*4 + r;
      out[((size_t)b*SEQ + qrow)*DIM + h*64 + df*16 + lr] = f2bf(o[df][r]*linv[r]);
    }
}

// ============================ fused per-layer weight transpose+convert (R8-proven) ============================
__global__ __launch_bounds__(256) void k_wtrans4(const float* __restrict__ Wq, const float* __restrict__ Wp,
                                                 const float* __restrict__ W1, const float* __restrict__ W2,
                                                 unsigned short* __restrict__ dq, unsigned short* __restrict__ dp,
                                                 unsigned short* __restrict__ d1, unsigned short* __restrict__ d2){
  int bid = blockIdx.x;
  const float* src; unsigned short* dst; int K, N, local;
  if (bid < 1728)      { src=Wq; dst=dq; K=768;  N=2304; local=bid; }
  else if (bid < 2304) { src=Wp; dst=dp; K=768;  N=768;  local=bid-1728; }
  else if (bid < 4608) { src=W1; dst=d1; K=768;  N=3072; local=bid-2304; }
  else                 { src=W2; dst=d2; K=3072; N=768;  local=bid-4608; }
  int nx = N/32;
  int n0 = (local % nx)*32, k0 = (local / nx)*32;
  __shared__ float tile[32][33];
  int tx = threadIdx.x & 31, ty = threadIdx.x >> 5;
#pragma unroll
  for (int r=0;r<32;r+=8)
    tile[ty+r][tx] = src[(size_t)(k0+ty+r)*N + n0+tx];
  __syncthreads();
#pragma unroll
  for (int r=0;r<32;r+=8)
    dst[(size_t)(n0+ty+r)*K + k0+tx] = f2bf(tile[tx][ty+r]);
}

// ============================ f32 -> bf16 bulk convert (tok_emb) ============================
__global__ void k_cvt(const float* __restrict__ src, unsigned short* __restrict__ dst, int n8){
  int i = blockIdx.x*blockDim.x + threadIdx.x;
  for (; i < n8; i += gridDim.x*blockDim.x){
    float4 f0 = ((const float4*)src)[i*2];
    float4 f1 = ((const float4*)src)[i*2+1];
    u16x8 v;
    v[0]=f2bf(f0.x); v[1]=f2bf(f0.y); v[2]=f2bf(f0.z); v[3]=f2bf(f0.w);
    v[4]=f2bf(f1.x); v[5]=f2bf(f1.y); v[6]=f2bf(f1.z); v[7]=f2bf(f1.w);
    ((u16x8*)dst)[i] = v;
  }
}

// ============================ MFMA bf16 GEMM (BK=32, XOR swizzle; WIDE/DBUF variants) ============================
// C(MxN) = A(MxK bf16,row) * B^T(NxK bf16,row). ACT 0/1(gelu). OUTBF: bf16 out.
// WIDE=false: 4 waves in 2x2, wave tile (BMT/2)x(BNT/2). WIDE=true: 4 waves in 1x4,
// wave tile BMT x (BNT/4) -> 32 MFMA per 12 fragment reads (-25% LDS bytes/FLOP).
// DBUF: double-buffered LDS, one barrier per K-step (R13); else 2-barrier (R12).
// grid: x = M/BMT (M-fastest), y = ceil(N/BNT); nwg % 8 == 0 required.
template<int ACT, bool OUTBF, int BMT, int BNT, bool NT, bool WIDE, bool DBUF>
__global__ __launch_bounds__(256) void k_mgemm(const unsigned short* __restrict__ A,
                                               const unsigned short* __restrict__ B,
                                               void* __restrict__ Cout,
                                               int M, int N, int K)
{
  constexpr int MF = WIDE ? BMT/16 : BMT/32;
  constexpr int NF = WIDE ? BNT/64 : BNT/32;
  constexpr int TILE = (BMT+BNT)*32;              // u16 per buffer
  __shared__ __align__(16) unsigned short Sm[(DBUF?2:1)*TILE];
  const int tid = threadIdx.x;
  const int l = tid & 63, w = tid >> 6;
  const int wr = w >> 1, wc = w & 1;
  const int mbase = WIDE ? 0 : wr*(BMT/2);        // wave's first M row
  const int nbase = WIDE ? w*(BNT/4) : wc*(BNT/2);// wave's first N col

  const int nwg  = gridDim.x * gridDim.y;
  const int flat = blockIdx.y * gridDim.x + blockIdx.x;
  const int q8   = nwg >> 3;
  const int wk   = (flat & 7) * q8 + (flat >> 3);
  const int bm = (wk % gridDim.x) * BMT;
  const int bn = (wk / gridDim.x) * BNT;

  const int srow = tid >> 2;                              // 0..63 (row within 64-row chunk)
  const int scol = (((tid & 3) ^ ((srow >> 1) & 3))) * 8; // inverse-swizzled global col

  f32x4 acc[MF][NF];
#pragma unroll
  for (int i=0;i<MF;i++)
#pragma unroll
    for (int j=0;j<NF;j++) acc[i][j] = (f32x4){0.f,0.f,0.f,0.f};

  auto STAGE = [&](int bufb, int k0){
    unsigned short* As = Sm + bufb*TILE;
    unsigned short* Bs = As + BMT*32;
#pragma unroll
    for (int c=0;c<BMT/64;++c){
      const unsigned short* ga = A + (size_t)(bm + c*64 + srow)*K + (k0 + scol);
      __builtin_amdgcn_global_load_lds(
          (const __attribute__((address_space(1))) void*)ga,
          (__attribute__((address_space(3))) void*)(As + c*2048 + w*512),
          16, 0, 0);
    }
#pragma unroll
    for (int c=0;c<BNT/64;++c){
      int gn = bn + c*64 + srow; if (gn >= N) gn = N-1;
      const unsigned short* gb = B + (size_t)gn*K + (k0 + scol);
      __builtin_amdgcn_global_load_lds(
          (const __attribute__((address_space(1))) void*)gb,
          (__attribute__((address_space(3))) void*)(Bs + c*2048 + w*512),
          16, 0, 0);
    }
  };

  auto COMPUTE = [&](int bufb){
    const unsigned short* As = Sm + bufb*TILE;
    const unsigned short* Bs = As + BMT*32;
    bf16x8 af[MF], bfr[NF];
#pragma unroll
    for (int i=0;i<MF;i++){
      int row  = mbase + i*16 + (l&15);
      int slot = (l>>4) ^ ((row>>1)&3);
      af[i]  = *(const bf16x8*)(As + (row*32 + slot*8));
    }
#pragma unroll
    for (int j=0;j<NF;j++){
      int row  = nbase + j*16 + (l&15);
      int slot = (l>>4) ^ ((row>>1)&3);
      bfr[j] = *(const bf16x8*)(Bs + (row*32 + slot*8));
    }
#pragma unroll
    for (int mi=0;mi<MF;mi++)
#pragma unroll
      for (int ni=0;ni<NF;ni++)
        acc[mi][ni] = __builtin_amdgcn_mfma_f32_16x16x32_bf16(af[mi], bfr[ni], acc[mi][ni], 0,0,0);
  };

  if constexpr (DBUF){
    STAGE(0, 0);
    __syncthreads();
    int cur = 0;
    for (int k0 = 32; k0 < K; k0 += 32){
      STAGE(cur^1, k0);
      COMPUTE(cur);
      __syncthreads();
      cur ^= 1;
    }
    COMPUTE(cur);
  } else {
    for (int k0 = 0; k0 < K; k0 += 32){
      STAGE(0, k0);
      __syncthreads();
      COMPUTE(0);
      __syncthreads();
    }
  }

  if constexpr (OUTBF){
#pragma unroll
    for (int mi=0;mi<MF;mi++){
      const int gm0 = bm + mbase + mi*16 + (l>>4)*4;
#pragma unroll
      for (int ni=0;ni<NF;ni++){
        const int gn = bn + nbase + ni*16 + (l&15);
        if (gn < N){
#pragma unroll
          for (int r=0;r<4;r++){
            float v = acc[mi][ni][r];
            if constexpr (ACT==1) v = 0.5f*v*(1.f + erff(v*0.70710678118654752f));
            ((unsigned short*)Cout)[(size_t)(gm0+r)*N + gn] = f2bf(v);
          }
        }
      }
    }
  } else {
    // LDS-band transpose epilogue: 16-row bands, f32x4 coalesced stores
    float* band = (float*)Sm;
#pragma unroll
    for (int b=0; b<BMT/16; ++b){
      __syncthreads();
      if constexpr (WIDE){
        // every wave writes its 64-col slice of band b (mi == b)
#pragma unroll
        for (int ni=0;ni<NF;ni++){
#pragma unroll
          for (int r=0;r<4;r++){
            float v = acc[b][ni][r];
            if constexpr (ACT==1) v = 0.5f*v*(1.f + erff(v*0.70710678118654752f));
            band[((l>>4)*4+r)*BNT + nbase + ni*16 + (l&15)] = v;
          }
        }
      } else {
#pragma unroll
        for (int mi=0;mi<MF;mi++){
          if (b == wr*MF + mi){
#pragma unroll
            for (int ni=0;ni<NF;ni++){
#pragma unroll
              for (int r=0;r<4;r++){
                float v = acc[mi][ni][r];
                if constexpr (ACT==1) v = 0.5f*v*(1.f + erff(v*0.70710678118654752f));
                band[((l>>4)*4+r)*BNT + nbase + ni*16 + (l&15)] = v;
              }
            }
          }
        }
      }
      __syncthreads();
      const int row0 = bm + b*16;
#pragma unroll
      for (int p=0; p<(4*BNT)/256; ++p){
        int f = tid + p*256;
        int row = f/(BNT/4), c4 = f%(BNT/4);
        f32x4 v = *(const f32x4*)&band[row*BNT + c4*4];
        float* cp = (float*)Cout + (size_t)(row0+row)*N + bn + c4*4;
        if (bn + c4*4 + 3 < N){
          if constexpr (NT) __builtin_nontemporal_store(v, (f32x4*)cp);
          else *(f32x4*)cp = v;
        } else {
#pragma unroll
          for (int j=0;j<4;j++) if (bn + c4*4 + j < N) cp[j] = v[j];
        }
      }
    }
  }
}

// ============================ host launch ============================
extern "C" void kernel_launch(void* const* d_in, const int* in_sizes, int n_in,
                              void* d_out, int out_size, void* d_ws, size_t ws_size,
                              hipStream_t stream) {
  const int*   ids   = (const int*)  d_in[0];
  const float* tok   = (const float*)d_in[1];
  const float* pos   = (const float*)d_in[2];
  const float* ln1g  = (const float*)d_in[3];
  const float* ln1b  = (const float*)d_in[4];
  const float* ln2g  = (const float*)d_in[5];
  const float* ln2b  = (const float*)d_in[6];
  const float* Wqkv  = (const float*)d_in[7];
  const float* Wproj = (const float*)d_in[8];
  const float* Wfc1  = (const float*)d_in[9];
  const float* Wfc2  = (const float*)d_in[10];
  const float* mAW   = (const float*)d_in[11];
  const float* mAb   = (const float*)d_in[12];
  const float* mAal  = (const float*)d_in[13];
  const float* mFW   = (const float*)d_in[14];
  const float* mFb   = (const float*)d_in[15];
  const float* mFal  = (const float*)d_in[16];
  const float* lnfg  = (const float*)d_in[17];
  const float* lnfb  = (const float*)d_in[18];
  float* out = (float*)d_out;

  float* ws   = (float*)d_ws;
  float* xA   = ws + O_X;
  float* xB   = ws + O_X2;
  unsigned short* ybf   = (unsigned short*)(ws + O_TMP);   // y bf16
  unsigned short* bigBF = (unsigned short*)(ws + O_BIG);   // qkv / fc1-out bf16
  unsigned short* lnbf  = (unsigned short*)(ws + O_LNB);
  unsigned short* t1bf  = (unsigned short*)(ws + O_T1B);
  float* coef = ws + O_COEF;
  unsigned short* wT    = (unsigned short*)(ws + O_WT);
  unsigned short* wqkvT  = wT;
  unsigned short* wprojT = wT + (size_t)2304*768;
  unsigned short* wfc1T  = wprojT + (size_t)768*768;
  unsigned short* wfc2T  = wfc1T + (size_t)3072*768;
  unsigned short* tokbf  = (unsigned short*)(ws + O_X);    // overlays dead buffers at lm_head time
  unsigned short* lnfbf  = (unsigned short*)(ws + O_LNF);

  float* xc = xA; float* xn = xB;
  for (int l=0; l<NLAYER; l++){
    k_wtrans4<<<6912, 256, 0, stream>>>(Wqkv + (size_t)l*DIM*3*DIM, Wproj + (size_t)l*DIM*DIM,
                                        Wfc1 + (size_t)l*DIM*FFDIM, Wfc2 + (size_t)l*FFDIM*DIM,
                                        wqkvT, wprojT, wfc1T, wfc2T);
    // ---- attention sublayer ----
    if (l == 0){
      k_mhc<true><<<NTOK, 256, 0, stream>>>(ids, tok, pos, nullptr, nullptr, xA,
                                            mAW, mAb, mAal, ln1g, ln1b, coef, lnbf);
    } else {
      k_mhc<false><<<NTOK, 256, 0, stream>>>(nullptr, nullptr, nullptr, xc, ybf, xn,
                                             mAW + (size_t)l*NDIM*NC, mAb + (size_t)l*NC, mAal + l,
                                             ln1g + (size_t)l*DIM, ln1b + (size_t)l*DIM, coef, lnbf);
      { float* tmp = xc; xc = xn; xn = tmp; }
    }
    k_mgemm<0,true ,64,128,false,false,true><<<dim3(32, 2304/128), 256, 0, stream>>>(lnbf, wqkvT, (void*)bigBF, NTOK, 2304, 768);
    k_fattn<<<dim3(SEQ/64, NHEAD, BATCH), 256, 0, stream>>>(bigBF, t1bf);
    k_mgemm<0,true ,64,64,false,false,true><<<dim3(32, 768/64), 256, 0, stream>>>(t1bf, wprojT, (void*)ybf, NTOK, 768, 768);

    // ---- ffn sublayer ----
    k_mhc<false><<<NTOK, 256, 0, stream>>>(nullptr, nullptr, nullptr, xc, ybf, xn,
                                           mFW + (size_t)l*NDIM*NC, mFb + (size_t)l*NC, mFal + l,
                                           ln2g + (size_t)l*DIM, ln2b + (size_t)l*DIM, coef, lnbf);
    { float* tmp = xc; xc = xn; xn = tmp; }
    k_mgemm<1,true ,64,128,false,false,true><<<dim3(32, 3072/128), 256, 0, stream>>>(lnbf, wfc1T, (void*)bigBF, NTOK, 3072, 768);
    k_mgemm<0,true ,64,64,false,false,true><<<dim3(32, 768/64), 256, 0, stream>>>(bigBF, wfc2T, (void*)ybf, NTOK, 768, 3072);
  }

  // tail: combine-sum + final LN, then lm_head on bf16 tok_emb
  k_csumln<<<NTOK, 256, 0, stream>>>(xc, coef, ybf, lnfg, lnfb, lnfbf);
  k_cvt<<<2048, 256, 0, stream>>>(tok, tokbf, (VOCAB*DIM)/8);
  // lm_head: WIDE wave tile 128x64 (MF=8,NF=4), single-buffer; grid 16x197 = 3152 (div 8)
  k_mgemm<0,false,128,256,true,true,false><<<dim3(16, (VOCAB+255)/256), 256, 0, stream>>>(lnfbf, tokbf, out, NTOK, VOCAB, 768);
}